// Round 16
// baseline (102.933 us; speedup 1.0000x reference)
//
#include <hip/hip_runtime.h>
#include <hip/hip_bf16.h>
#include <math.h>

#define B_SZ 2048
#define NF 1024
#define NH 2048
#define NCq 128
#define MMq 20
#define NY 2580            // M*NC+M
#define NYPAD 2688         // 21*128
#define QP_ITERS 56

#define XN4  (B_SZ * NF / 4)
#define W1N4 (NH * NF / 4)
#define W2N4 (NY * NH / 4)
#define CVT_TOT (XN4 + W1N4 + W2N4)

#define YBYTES ((size_t)B_SZ * NY * 4)          // 21.1 MB per partial
#define WS_Y0  27787264
#define WS_NEED_SPLIT (WS_Y0 + 2 * YBYTES)

typedef unsigned short u16;
typedef __bf16 bf16x8 __attribute__((ext_vector_type(8)));
typedef float f32x4 __attribute__((ext_vector_type(4)));

static __device__ __forceinline__ u16 f32_to_bf16(float f) {
  unsigned u = __float_as_uint(f);
  u += 0x7FFFu + ((u >> 16) & 1u);
  return (u16)(u >> 16);
}

static __device__ __forceinline__ float bcast(float v, int lane) {
  return __uint_as_float(__builtin_amdgcn_readlane(__float_as_uint(v), lane));
}

static __device__ __forceinline__ void gload16(const void* g, void* lds) {
  __builtin_amdgcn_global_load_lds(
      (const __attribute__((address_space(1))) void*)g,
      (__attribute__((address_space(3))) void*)lds, 16, 0, 0);
}

// ---------------- single fused convert: x | W1 | W2(real rows) ----------------
__global__ __launch_bounds__(256) void cvt_all_kernel(const float* __restrict__ x,
                                                      const float* __restrict__ W1,
                                                      const float* __restrict__ W2,
                                                      u16* __restrict__ xb,
                                                      u16* __restrict__ w1b,
                                                      u16* __restrict__ w2b) {
  const int i = blockIdx.x * 256 + threadIdx.x;
  const float* src;
  u16* dst;
  int j;
  if (i < XN4)              { src = x;  dst = xb;  j = i; }
  else if (i < XN4 + W1N4)  { src = W1; dst = w1b; j = i - XN4; }
  else                      { src = W2; dst = w2b; j = i - XN4 - W1N4; }
  float4 v = ((const float4*)src)[j];
  ushort4 o;
  o.x = f32_to_bf16(v.x); o.y = f32_to_bf16(v.y);
  o.z = f32_to_bf16(v.z); o.w = f32_to_bf16(v.w);
  ((ushort4*)dst)[j] = o;
}

// ---------------- GEMM: C = A(M x lda) * B(N x lda)^T + bias, tile 64x128 ----
// DEPTH-3 counted-vmcnt pipeline: 3 LDS buffers, prologue stages tiles 0,1,2
// (18 loads in flight); steady state waits vmcnt(12) -> issue-to-wait distance
// ~2 iterations (~2500cy), covering HBM-class latency (depth-2's ~1 iter did
// not -- per-block-iter cost was invariant ~1290cy across R8-R15 configs).
// T2 both-sides 16B-chunk swizzle (0 conflicts verified); bijective XCD swizzle.
// SPLIT-K (OUTMODE 1, nhalf>0): s=1 blocks do the second K-half into Cf1,
// no bias; qp sums partials. OUTMODE 0: bf16 out + relu.
template<int KEXT, int OUTMODE>
__global__ __launch_bounds__(256) void gemm_bt_kernel(
    const u16* __restrict__ A, const u16* __restrict__ Bm,
    const float* __restrict__ bias,
    u16* __restrict__ Cb, float* __restrict__ Cf0, float* __restrict__ Cf1,
    int ldc, int ncols, int nxt, int lda, int nhalf) {
  __shared__ u16 As[3][2][64 * 32];    // [buf][ksub] 4 KB planes, 24 KB
  __shared__ u16 Bs[3][2][128 * 32];   // [buf][ksub] 8 KB planes, 48 KB
  const int tid = threadIdx.x;
  const int w = tid >> 6;
  const int l = tid & 63;

  // bijective XCD swizzle: gridDim.x % 8 == 0
  const int chunk = gridDim.x >> 3;
  const int swz = (blockIdx.x & 7) * chunk + (blockIdx.x >> 3);
  int s = 0, idx = swz;
  if (OUTMODE == 1 && nhalf > 0) { s = swz >= nhalf; idx = swz - s * nhalf; }
  const int m0 = (idx / nxt) * 64;
  const int n0 = (idx % nxt) * 128;
  const u16* Ab = A  + (size_t)s * KEXT;
  const u16* Bb = Bm + (size_t)s * KEXT;
  float* Cf = s ? Cf1 : Cf0;

  // staging: physical chunk p per plane -> row p>>2, phys-kp p&3;
  // logical k-chunk = (p&3) ^ ((row>>1)&3)
  const int srow = tid >> 2;
  const int kps = (tid & 3) ^ ((tid >> 3) & 3);
  const u16* gA0 = Ab + (size_t)(m0 + srow) * lda + kps * 8;
  const u16* gB0 = Bb + (size_t)(n0 + srow) * lda + kps * 8;
  const u16* gB1 = Bb + (size_t)(n0 + 64 + srow) * lda + kps * 8;
  char* lA = (char*)As;
  char* lB = (char*)Bs;
  const int lbW = w * 1024;            // wave-uniform byte offset within a plane

  // wave -> 32x64 output sub-tile: wm in {0,32}, wn in {0,64}
  const int wm = (w >> 1) * 32, wn = (w & 1) * 64;
  const int lrow = l & 15;
  const int kc = ((l >> 4) ^ ((lrow >> 1) & 3)) * 16;   // swizzled 16B chunk
  int aoff[2], boff[4];
#pragma unroll
  for (int i = 0; i < 2; ++i) aoff[i] = (wm + i * 16 + lrow) * 64 + kc;
#pragma unroll
  for (int i = 0; i < 4; ++i) boff[i] = (wn + i * 16 + lrow) * 64 + kc;

  f32x4 acc[2][4];
#pragma unroll
  for (int i = 0; i < 2; ++i)
#pragma unroll
    for (int j = 0; j < 4; ++j) acc[i][j] = (f32x4){0.f, 0.f, 0.f, 0.f};

  constexpr int NT = KEXT / 64;        // 16 (split/gemm1) or 32 (fallback)

  auto STAGE = [&](int t, int buf) {   // 6 gload16
#pragma unroll
    for (int ks = 0; ks < 2; ++ks) {
      const int koff = t * 64 + ks * 32;
      gload16(gA0 + koff, lA + buf * 8192  + ks * 4096 + lbW);
      gload16(gB0 + koff, lB + buf * 16384 + ks * 8192 + lbW);
      gload16(gB1 + koff, lB + buf * 16384 + ks * 8192 + 4096 + lbW);
    }
  };
  auto COMPUTE = [&](int buf) {        // 12 ds_read_b128 + 16 MFMA
#pragma unroll
    for (int ks = 0; ks < 2; ++ks) {
      const char* pa = lA + buf * 8192  + ks * 4096;
      const char* pb = lB + buf * 16384 + ks * 8192;
      bf16x8 af[2], bfr[4];
#pragma unroll
      for (int i = 0; i < 2; ++i) af[i] = *(const bf16x8*)(pa + aoff[i]);
#pragma unroll
      for (int i = 0; i < 4; ++i) bfr[i] = *(const bf16x8*)(pb + boff[i]);
#pragma unroll
      for (int mi = 0; mi < 2; ++mi)
#pragma unroll
        for (int ni = 0; ni < 4; ++ni)
          acc[mi][ni] = __builtin_amdgcn_mfma_f32_16x16x32_bf16(af[mi], bfr[ni], acc[mi][ni], 0, 0, 0);
    }
  };

  // prologue: 3 tiles in flight (18 loads)
  STAGE(0, 0);
  STAGE(1, 1);
  STAGE(2, 2);

#pragma unroll
  for (int kt = 0; kt < NT; ++kt) {
    // counted wait: retire tile kt's 6 loads; deeper tiles stay in flight
    if (kt + 2 < NT)      asm volatile("s_waitcnt vmcnt(12)" ::: "memory");
    else if (kt + 1 < NT) asm volatile("s_waitcnt vmcnt(6)" ::: "memory");
    else                  asm volatile("s_waitcnt vmcnt(0)" ::: "memory");
    __builtin_amdgcn_s_barrier();                      // all waves' writes visible
    __builtin_amdgcn_sched_barrier(0);
    COMPUTE(kt % 3);
    __builtin_amdgcn_sched_barrier(0);
    __builtin_amdgcn_s_barrier();                      // all waves done reading buf
    __builtin_amdgcn_sched_barrier(0);
    if (kt + 3 < NT) STAGE(kt + 3, kt % 3);            // refill freed buffer
  }

  // epilogue: C row = m0+wm+mi*16+(l>>4)*4+r ; col = n0+wn+ni*16+(l&15)
#pragma unroll
  for (int mi = 0; mi < 2; ++mi) {
    const int row = m0 + wm + mi * 16 + (l >> 4) * 4;
#pragma unroll
    for (int ni = 0; ni < 4; ++ni) {
      const int col = n0 + wn + ni * 16 + (l & 15);
      if (OUTMODE == 1 && col >= ncols) continue;
      const float bv = (OUTMODE == 0 || s == 0) ? bias[col] : 0.f;
#pragma unroll
      for (int r = 0; r < 4; ++r) {
        float v = acc[mi][ni][r] + bv;
        if (OUTMODE == 0) {
          v = fmaxf(v, 0.f);
          Cb[(size_t)(row + r) * ldc + col] = f32_to_bf16(v);
        } else {
          Cf[(size_t)(row + r) * ldc + col] = v;
        }
      }
    }
  }
}

// ---------------- QP solve + log_softmax ----------------
// 4 waves/block, ONE problem per wave. If y1 != null, y = y0 + y1 (split-K
// partial sum fused into the G-staging loads). Broadcasts via v_readlane.
__global__ __launch_bounds__(256) void qp_kernel(const float* __restrict__ y0,
                                                 const float* __restrict__ y1,
                                                 float* __restrict__ out) {
  __shared__ float Gs[4][MMq][132];    // row pad 132: staging/epilogue conflict-free
  __shared__ float GGs[4][MMq][21];    // row pad 21: gcd(21,32)=1, conflict-free
  __shared__ float cs[4][MMq];
  const int tid = threadIdx.x;
  const int wid = tid >> 6, l = tid & 63;
  const int b = blockIdx.x * 4 + wid;
  const float* yb0 = y0 + (size_t)b * NY;
  const float* yb1 = y1 ? y1 + (size_t)b * NY : nullptr;

  // stage G (20x128) -- own wave only; fused split-K sum
  for (int idx = l; idx < MMq * NCq / 4; idx += 64) {
    const int r = idx >> 5;
    const int kk = (idx & 31) * 4;
    float4 v = ((const float4*)yb0)[idx];
    if (yb1) {
      float4 u = ((const float4*)yb1)[idx];
      v.x += u.x; v.y += u.y; v.z += u.z; v.w += u.w;
    }
    *(float4*)&Gs[wid][r][kk] = v;
  }

  // GG = G G^T (upper triangle, mirrored) -- own wave
  for (int idx = l; idx < 210; idx += 64) {
    int i = 0, rem = idx;
    while (rem >= MMq - i) { rem -= MMq - i; ++i; }
    const int j = i + rem;
    float s = 0.f;
    for (int kk = 0; kk < NCq; kk += 4) {
      float4 a = *(const float4*)&Gs[wid][i][kk];
      float4 c4 = *(const float4*)&Gs[wid][j][kk];
      s += a.x * c4.x + a.y * c4.y + a.z * c4.z + a.w * c4.w;
    }
    GGs[wid][i][j] = s;
    GGs[wid][j][i] = s;
  }
  // c_i = sum_j G_ij + h_i
  if (l < MMq) {
    float s = 0.f;
    for (int kk = 0; kk < NCq; kk += 4) {
      float4 a = *(const float4*)&Gs[wid][l][kk];
      s += (a.x + a.y) + (a.z + a.w);
    }
    float h = yb0[MMq * NCq + l];
    if (yb1) h += yb1[MMq * NCq + l];
    cs[wid][l] = s + h;
  }

  const bool act = (l < MMq);
  float gg[MMq];
#pragma unroll
  for (int j = 0; j < MMq; ++j) gg[j] = act ? GGs[wid][l][j] : 0.f;
  const float ci = act ? cs[wid][l] : 0.f;

  // L = max_i sum_j |GG_ij| (inf-norm >= lambda_max; fixed point step-independent)
  float rs = 0.f;
#pragma unroll
  for (int j = 0; j < MMq; ++j) rs += fabsf(gg[j]);
#pragma unroll
  for (int m = 1; m < 64; m <<= 1) rs = fmaxf(rs, __shfl_xor(rs, m, 64));
  const float invL = 1.0f / (rs + 1e-6f);

  // FISTA, momentum beta_k = k/(k+3)
  float lam = 0.f, yv = 0.f, fi = 0.f;
  for (int it = 0; it < QP_ITERS; ++it) {
    float ys[MMq];
#pragma unroll
    for (int j = 0; j < MMq; ++j) ys[j] = bcast(yv, j);   // 20x v_readlane -> SGPR
    float g0 = ci, g1 = 0.f, g2 = 0.f, g3 = 0.f;
#pragma unroll
    for (int j = 0; j < MMq; j += 4) {
      g0 = fmaf(gg[j + 0], ys[j + 0], g0);
      g1 = fmaf(gg[j + 1], ys[j + 1], g1);
      g2 = fmaf(gg[j + 2], ys[j + 2], g2);
      g3 = fmaf(gg[j + 3], ys[j + 3], g3);
    }
    const float grad = (g0 + g1) + (g2 + g3);
    const float ln = fmaxf(fmaf(-grad, invL, yv), 0.f);
    const float beta = fi * __builtin_amdgcn_rcpf(fi + 3.0f);  // off critical path
    yv = fmaf(beta, ln - lam, ln);
    lam = ln;
    fi += 1.0f;
  }

  // broadcast lam to SGPRs; z_j = -(1 + sum_i G_ij lam_i); log_softmax over 128
  float ls[MMq];
#pragma unroll
  for (int j = 0; j < MMq; ++j) ls[j] = bcast(lam, j);

  float z0 = 1.f, z1 = 1.f;
#pragma unroll
  for (int ii = 0; ii < MMq; ++ii) {
    z0 = fmaf(Gs[wid][ii][l], ls[ii], z0);
    z1 = fmaf(Gs[wid][ii][l + 64], ls[ii], z1);
  }
  z0 = -z0; z1 = -z1;

  float mx = fmaxf(z0, z1);
#pragma unroll
  for (int m = 1; m < 64; m <<= 1) mx = fmaxf(mx, __shfl_xor(mx, m, 64));
  float sm = __expf(z0 - mx) + __expf(z1 - mx);
#pragma unroll
  for (int m = 1; m < 64; m <<= 1) sm += __shfl_xor(sm, m, 64);
  const float lse = mx + __logf(sm);
  float* ob = out + (size_t)b * NCq;
  ob[l] = z0 - lse;
  ob[l + 64] = z1 - lse;
}

// ---------------- launch ----------------
extern "C" void kernel_launch(void* const* d_in, const int* in_sizes, int n_in,
                              void* d_out, int out_size, void* d_ws, size_t ws_size,
                              hipStream_t stream) {
  const float* x  = (const float*)d_in[0];
  const float* W1 = (const float*)d_in[1];
  const float* b1 = (const float*)d_in[2];
  const float* W2 = (const float*)d_in[3];
  const float* b2 = (const float*)d_in[4];
  float* out = (float*)d_out;
  char* ws = (char*)d_ws;

  u16*   xb  = (u16*)(ws);                       //  4 MiB
  u16*   w1b = (u16*)(ws + 4194304);             //  4 MiB
  u16*   w2b = (u16*)(ws + 8388608);             // 10.5 MiB (pad rows stale, never stored)
  u16*   h1b = (u16*)(ws + 19398656);            //  8 MiB
  float* yb0 = (float*)(ws + WS_Y0);             // 21.1 MiB partial 0 (with bias)
  float* yb1 = (float*)(ws + WS_Y0 + YBYTES);    // 21.1 MiB partial 1 (split-K only)

  const bool splitk = ws_size >= WS_NEED_SPLIT;

  cvt_all_kernel<<<CVT_TOT / 256, 256, 0, stream>>>(x, W1, W2, xb, w1b, w2b);

  // gemm1: K=1024 full, grid 512 (%8==0)
  gemm_bt_kernel<1024, 0><<<(NH / 128) * (B_SZ / 64), 256, 0, stream>>>(
      xb, w1b, b1, h1b, nullptr, nullptr, NH, NH, NH / 128, NF, 0);

  if (splitk) {
    // gemm2 split-K=2: one launch, grid 1344 (%8==0); halves -> yb0 / yb1
    gemm_bt_kernel<1024, 1><<<2 * (NYPAD / 128) * (B_SZ / 64), 256, 0, stream>>>(
        h1b, w2b, b2, nullptr, yb0, yb1, NY, NY, NYPAD / 128, NH,
        (NYPAD / 128) * (B_SZ / 64));
    qp_kernel<<<B_SZ / 4, 256, 0, stream>>>(yb0, yb1, out);
  } else {
    // fallback: single full-K gemm2
    gemm_bt_kernel<2048, 1><<<(NYPAD / 128) * (B_SZ / 64), 256, 0, stream>>>(
        h1b, w2b, b2, nullptr, yb0, nullptr, NY, NY, NYPAD / 128, NH, 0);
    qp_kernel<<<B_SZ / 4, 256, 0, stream>>>(yb0, nullptr, out);
  }
}

// Round 17
// 100.035 us; speedup vs baseline: 1.0290x; 1.0290x over previous
//
#include <hip/hip_runtime.h>
#include <hip/hip_bf16.h>
#include <math.h>

#define B_SZ 2048
#define NF 1024
#define NH 2048
#define NCq 128
#define MMq 20
#define NY 2580            // M*NC+M
#define NYPAD 2688         // 21*128
#define QP_ITERS 40        // residual ~e^-12; absmax bit-invariant 500->56 (6 pts)

#define XN4  (B_SZ * NF / 4)
#define W1N4 (NH * NF / 4)
#define W2N4 (NY * NH / 4)
#define CVT_TOT (XN4 + W1N4 + W2N4)

#define YBYTES ((size_t)B_SZ * NY * 4)          // 21.1 MB per partial
#define WS_Y0  27787264
#define WS_NEED_SPLIT (WS_Y0 + 2 * YBYTES)

typedef unsigned short u16;
typedef __bf16 bf16x8 __attribute__((ext_vector_type(8)));
typedef float f32x4 __attribute__((ext_vector_type(4)));

static __device__ __forceinline__ u16 f32_to_bf16(float f) {
  unsigned u = __float_as_uint(f);
  u += 0x7FFFu + ((u >> 16) & 1u);
  return (u16)(u >> 16);
}

static __device__ __forceinline__ float bcast(float v, int lane) {
  return __uint_as_float(__builtin_amdgcn_readlane(__float_as_uint(v), lane));
}

static __device__ __forceinline__ void gload16(const void* g, void* lds) {
  __builtin_amdgcn_global_load_lds(
      (const __attribute__((address_space(1))) void*)g,
      (__attribute__((address_space(3))) void*)lds, 16, 0, 0);
}

// ---------------- single fused convert: x | W1 | W2(real rows) ----------------
__global__ __launch_bounds__(256) void cvt_all_kernel(const float* __restrict__ x,
                                                      const float* __restrict__ W1,
                                                      const float* __restrict__ W2,
                                                      u16* __restrict__ xb,
                                                      u16* __restrict__ w1b,
                                                      u16* __restrict__ w2b) {
  const int i = blockIdx.x * 256 + threadIdx.x;
  const float* src;
  u16* dst;
  int j;
  if (i < XN4)              { src = x;  dst = xb;  j = i; }
  else if (i < XN4 + W1N4)  { src = W1; dst = w1b; j = i - XN4; }
  else                      { src = W2; dst = w2b; j = i - XN4 - W1N4; }
  float4 v = ((const float4*)src)[j];
  ushort4 o;
  o.x = f32_to_bf16(v.x); o.y = f32_to_bf16(v.y);
  o.z = f32_to_bf16(v.z); o.w = f32_to_bf16(v.w);
  ((ushort4*)dst)[j] = o;
}

// ---------------- GEMM: C = A(M x lda) * B(N x lda)^T + bias, tile 64x128 ----
// SINGLE-BARRIER depth-3 rotation: iter kt = {STAGE(kt+2 -> buf[(kt+2)%3]);
// COMPUTE(buf[kt%3]); vmcnt(6); s_barrier}. The end-of-iter barrier proves BOTH
// (a) all waves' tile-(kt+1) loads retired (counted wait precedes it) and
// (b) all waves done reading buf[kt%3] (re-staged 2 iters later) -- one barrier
// per K-step instead of two (m233: the sync ritual is ~72% of 2-phase cost;
// per-block-iter cost was invariant ~1290cy across all R8-R16 configs).
// No sched_barrier(0) (m141: order-pinning regresses); asm memory clobbers +
// empty-asm fences after barriers provide compiler-level ordering.
// T2 both-sides swizzle (0 conflicts verified); bijective XCD swizzle.
// SPLIT-K (OUTMODE 1, nhalf>0): s=1 blocks -> second K-half into Cf1, no bias.
template<int KEXT, int OUTMODE>
__global__ __launch_bounds__(256) void gemm_bt_kernel(
    const u16* __restrict__ A, const u16* __restrict__ Bm,
    const float* __restrict__ bias,
    u16* __restrict__ Cb, float* __restrict__ Cf0, float* __restrict__ Cf1,
    int ldc, int ncols, int nxt, int lda, int nhalf) {
  __shared__ u16 As[3][2][64 * 32];    // [buf][ksub] 4 KB planes, 24 KB
  __shared__ u16 Bs[3][2][128 * 32];   // [buf][ksub] 8 KB planes, 48 KB
  const int tid = threadIdx.x;
  const int w = tid >> 6;
  const int l = tid & 63;

  // bijective XCD swizzle: gridDim.x % 8 == 0
  const int chunk = gridDim.x >> 3;
  const int swz = (blockIdx.x & 7) * chunk + (blockIdx.x >> 3);
  int s = 0, idx = swz;
  if (OUTMODE == 1 && nhalf > 0) { s = swz >= nhalf; idx = swz - s * nhalf; }
  const int m0 = (idx / nxt) * 64;
  const int n0 = (idx % nxt) * 128;
  const u16* Ab = A  + (size_t)s * KEXT;
  const u16* Bb = Bm + (size_t)s * KEXT;
  float* Cf = s ? Cf1 : Cf0;

  // staging: physical chunk p per plane -> row p>>2, phys-kp p&3;
  // logical k-chunk = (p&3) ^ ((row>>1)&3)
  const int srow = tid >> 2;
  const int kps = (tid & 3) ^ ((tid >> 3) & 3);
  const u16* gA0 = Ab + (size_t)(m0 + srow) * lda + kps * 8;
  const u16* gB0 = Bb + (size_t)(n0 + srow) * lda + kps * 8;
  const u16* gB1 = Bb + (size_t)(n0 + 64 + srow) * lda + kps * 8;
  char* lA = (char*)As;
  char* lB = (char*)Bs;
  const int lbW = w * 1024;            // wave-uniform byte offset within a plane

  // wave -> 32x64 output sub-tile: wm in {0,32}, wn in {0,64}
  const int wm = (w >> 1) * 32, wn = (w & 1) * 64;
  const int lrow = l & 15;
  const int kc = ((l >> 4) ^ ((lrow >> 1) & 3)) * 16;   // swizzled 16B chunk
  int aoff[2], boff[4];
#pragma unroll
  for (int i = 0; i < 2; ++i) aoff[i] = (wm + i * 16 + lrow) * 64 + kc;
#pragma unroll
  for (int i = 0; i < 4; ++i) boff[i] = (wn + i * 16 + lrow) * 64 + kc;

  f32x4 acc[2][4];
#pragma unroll
  for (int i = 0; i < 2; ++i)
#pragma unroll
    for (int j = 0; j < 4; ++j) acc[i][j] = (f32x4){0.f, 0.f, 0.f, 0.f};

  constexpr int NT = KEXT / 64;        // 16 (split/gemm1) or 32 (fallback)

  auto STAGE = [&](int t, int buf) {   // 6 gload16
#pragma unroll
    for (int ks = 0; ks < 2; ++ks) {
      const int koff = t * 64 + ks * 32;
      gload16(gA0 + koff, lA + buf * 8192  + ks * 4096 + lbW);
      gload16(gB0 + koff, lB + buf * 16384 + ks * 8192 + lbW);
      gload16(gB1 + koff, lB + buf * 16384 + ks * 8192 + 4096 + lbW);
    }
  };
  auto COMPUTE = [&](int buf) {        // 12 ds_read_b128 + 16 MFMA
#pragma unroll
    for (int ks = 0; ks < 2; ++ks) {
      const char* pa = lA + buf * 8192  + ks * 4096;
      const char* pb = lB + buf * 16384 + ks * 8192;
      bf16x8 af[2], bfr[4];
#pragma unroll
      for (int i = 0; i < 2; ++i) af[i] = *(const bf16x8*)(pa + aoff[i]);
#pragma unroll
      for (int i = 0; i < 4; ++i) bfr[i] = *(const bf16x8*)(pb + boff[i]);
#pragma unroll
      for (int mi = 0; mi < 2; ++mi)
#pragma unroll
        for (int ni = 0; ni < 4; ++ni)
          acc[mi][ni] = __builtin_amdgcn_mfma_f32_16x16x32_bf16(af[mi], bfr[ni], acc[mi][ni], 0, 0, 0);
    }
  };

  // prologue: 2 tiles in flight; retire tile 0 before first read
  STAGE(0, 0);
  STAGE(1, 1);
  asm volatile("s_waitcnt vmcnt(6)" ::: "memory");
  __builtin_amdgcn_s_barrier();
  asm volatile("" ::: "memory");

  int sb = 2, cb = 0;                  // stage / compute buffer indices (mod 3)
  for (int kt = 0; kt < NT; ++kt) {
    if (kt + 2 < NT) STAGE(kt + 2, sb);
    COMPUTE(cb);
    if (kt + 1 < NT) {
      // retire tile kt+1 for ALL waves; tile kt+2 (if any) stays in flight
      if (kt + 2 < NT) asm volatile("s_waitcnt vmcnt(6)" ::: "memory");
      else             asm volatile("s_waitcnt vmcnt(0)" ::: "memory");
      __builtin_amdgcn_s_barrier();
      asm volatile("" ::: "memory");
    }
    sb = (sb == 2) ? 0 : sb + 1;
    cb = (cb == 2) ? 0 : cb + 1;
  }

  // epilogue: C row = m0+wm+mi*16+(l>>4)*4+r ; col = n0+wn+ni*16+(l&15)
#pragma unroll
  for (int mi = 0; mi < 2; ++mi) {
    const int row = m0 + wm + mi * 16 + (l >> 4) * 4;
#pragma unroll
    for (int ni = 0; ni < 4; ++ni) {
      const int col = n0 + wn + ni * 16 + (l & 15);
      if (OUTMODE == 1 && col >= ncols) continue;
      const float bv = (OUTMODE == 0 || s == 0) ? bias[col] : 0.f;
#pragma unroll
      for (int r = 0; r < 4; ++r) {
        float v = acc[mi][ni][r] + bv;
        if (OUTMODE == 0) {
          v = fmaxf(v, 0.f);
          Cb[(size_t)(row + r) * ldc + col] = f32_to_bf16(v);
        } else {
          Cf[(size_t)(row + r) * ldc + col] = v;
        }
      }
    }
  }
}

// ---------------- QP solve + log_softmax ----------------
// 4 waves/block, ONE problem per wave. If y1 != null, y = y0 + y1 (split-K
// partial sum fused into the G-staging loads). Broadcasts via v_readlane.
__global__ __launch_bounds__(256) void qp_kernel(const float* __restrict__ y0,
                                                 const float* __restrict__ y1,
                                                 float* __restrict__ out) {
  __shared__ float Gs[4][MMq][132];    // row pad 132: staging/epilogue conflict-free
  __shared__ float GGs[4][MMq][21];    // row pad 21: gcd(21,32)=1, conflict-free
  __shared__ float cs[4][MMq];
  const int tid = threadIdx.x;
  const int wid = tid >> 6, l = tid & 63;
  const int b = blockIdx.x * 4 + wid;
  const float* yb0 = y0 + (size_t)b * NY;
  const float* yb1 = y1 ? y1 + (size_t)b * NY : nullptr;

  // stage G (20x128) -- own wave only; fused split-K sum
  for (int idx = l; idx < MMq * NCq / 4; idx += 64) {
    const int r = idx >> 5;
    const int kk = (idx & 31) * 4;
    float4 v = ((const float4*)yb0)[idx];
    if (yb1) {
      float4 u = ((const float4*)yb1)[idx];
      v.x += u.x; v.y += u.y; v.z += u.z; v.w += u.w;
    }
    *(float4*)&Gs[wid][r][kk] = v;
  }

  // GG = G G^T (upper triangle, mirrored) -- own wave
  for (int idx = l; idx < 210; idx += 64) {
    int i = 0, rem = idx;
    while (rem >= MMq - i) { rem -= MMq - i; ++i; }
    const int j = i + rem;
    float s = 0.f;
    for (int kk = 0; kk < NCq; kk += 4) {
      float4 a = *(const float4*)&Gs[wid][i][kk];
      float4 c4 = *(const float4*)&Gs[wid][j][kk];
      s += a.x * c4.x + a.y * c4.y + a.z * c4.z + a.w * c4.w;
    }
    GGs[wid][i][j] = s;
    GGs[wid][j][i] = s;
  }
  // c_i = sum_j G_ij + h_i
  if (l < MMq) {
    float s = 0.f;
    for (int kk = 0; kk < NCq; kk += 4) {
      float4 a = *(const float4*)&Gs[wid][l][kk];
      s += (a.x + a.y) + (a.z + a.w);
    }
    float h = yb0[MMq * NCq + l];
    if (yb1) h += yb1[MMq * NCq + l];
    cs[wid][l] = s + h;
  }

  const bool act = (l < MMq);
  float gg[MMq];
#pragma unroll
  for (int j = 0; j < MMq; ++j) gg[j] = act ? GGs[wid][l][j] : 0.f;
  const float ci = act ? cs[wid][l] : 0.f;

  // L = max_i sum_j |GG_ij| (inf-norm >= lambda_max; fixed point step-independent)
  float rs = 0.f;
#pragma unroll
  for (int j = 0; j < MMq; ++j) rs += fabsf(gg[j]);
#pragma unroll
  for (int m = 1; m < 64; m <<= 1) rs = fmaxf(rs, __shfl_xor(rs, m, 64));
  const float invL = 1.0f / (rs + 1e-6f);

  // FISTA, momentum beta_k = k/(k+3)
  float lam = 0.f, yv = 0.f, fi = 0.f;
  for (int it = 0; it < QP_ITERS; ++it) {
    float ys[MMq];
#pragma unroll
    for (int j = 0; j < MMq; ++j) ys[j] = bcast(yv, j);   // 20x v_readlane -> SGPR
    float g0 = ci, g1 = 0.f, g2 = 0.f, g3 = 0.f;
#pragma unroll
    for (int j = 0; j < MMq; j += 4) {
      g0 = fmaf(gg[j + 0], ys[j + 0], g0);
      g1 = fmaf(gg[j + 1], ys[j + 1], g1);
      g2 = fmaf(gg[j + 2], ys[j + 2], g2);
      g3 = fmaf(gg[j + 3], ys[j + 3], g3);
    }
    const float grad = (g0 + g1) + (g2 + g3);
    const float ln = fmaxf(fmaf(-grad, invL, yv), 0.f);
    const float beta = fi * __builtin_amdgcn_rcpf(fi + 3.0f);  // off critical path
    yv = fmaf(beta, ln - lam, ln);
    lam = ln;
    fi += 1.0f;
  }

  // broadcast lam to SGPRs; z_j = -(1 + sum_i G_ij lam_i); log_softmax over 128
  float ls[MMq];
#pragma unroll
  for (int j = 0; j < MMq; ++j) ls[j] = bcast(lam, j);

  float z0 = 1.f, z1 = 1.f;
#pragma unroll
  for (int ii = 0; ii < MMq; ++ii) {
    z0 = fmaf(Gs[wid][ii][l], ls[ii], z0);
    z1 = fmaf(Gs[wid][ii][l + 64], ls[ii], z1);
  }
  z0 = -z0; z1 = -z1;

  float mx = fmaxf(z0, z1);
#pragma unroll
  for (int m = 1; m < 64; m <<= 1) mx = fmaxf(mx, __shfl_xor(mx, m, 64));
  float sm = __expf(z0 - mx) + __expf(z1 - mx);
#pragma unroll
  for (int m = 1; m < 64; m <<= 1) sm += __shfl_xor(sm, m, 64);
  const float lse = mx + __logf(sm);
  float* ob = out + (size_t)b * NCq;
  ob[l] = z0 - lse;
  ob[l + 64] = z1 - lse;
}

// ---------------- launch ----------------
extern "C" void kernel_launch(void* const* d_in, const int* in_sizes, int n_in,
                              void* d_out, int out_size, void* d_ws, size_t ws_size,
                              hipStream_t stream) {
  const float* x  = (const float*)d_in[0];
  const float* W1 = (const float*)d_in[1];
  const float* b1 = (const float*)d_in[2];
  const float* W2 = (const float*)d_in[3];
  const float* b2 = (const float*)d_in[4];
  float* out = (float*)d_out;
  char* ws = (char*)d_ws;

  u16*   xb  = (u16*)(ws);                       //  4 MiB
  u16*   w1b = (u16*)(ws + 4194304);             //  4 MiB
  u16*   w2b = (u16*)(ws + 8388608);             // 10.5 MiB (pad rows stale, never stored)
  u16*   h1b = (u16*)(ws + 19398656);            //  8 MiB
  float* yb0 = (float*)(ws + WS_Y0);             // 21.1 MiB partial 0 (with bias)
  float* yb1 = (float*)(ws + WS_Y0 + YBYTES);    // 21.1 MiB partial 1 (split-K only)

  const bool splitk = ws_size >= WS_NEED_SPLIT;

  cvt_all_kernel<<<CVT_TOT / 256, 256, 0, stream>>>(x, W1, W2, xb, w1b, w2b);

  // gemm1: K=1024 full, grid 512 (%8==0)
  gemm_bt_kernel<1024, 0><<<(NH / 128) * (B_SZ / 64), 256, 0, stream>>>(
      xb, w1b, b1, h1b, nullptr, nullptr, NH, NH, NH / 128, NF, 0);

  if (splitk) {
    // gemm2 split-K=2: one launch, grid 1344 (%8==0); halves -> yb0 / yb1
    gemm_bt_kernel<1024, 1><<<2 * (NYPAD / 128) * (B_SZ / 64), 256, 0, stream>>>(
        h1b, w2b, b2, nullptr, yb0, yb1, NY, NY, NYPAD / 128, NH,
        (NYPAD / 128) * (B_SZ / 64));
    qp_kernel<<<B_SZ / 4, 256, 0, stream>>>(yb0, yb1, out);
  } else {
    // fallback: single full-K gemm2
    gemm_bt_kernel<2048, 1><<<(NYPAD / 128) * (B_SZ / 64), 256, 0, stream>>>(
        h1b, w2b, b2, nullptr, yb0, nullptr, NY, NY, NYPAD / 128, NH, 0);
    qp_kernel<<<B_SZ / 4, 256, 0, stream>>>(yb0, nullptr, out);
  }
}

// Round 18
// 86.344 us; speedup vs baseline: 1.1921x; 1.1586x over previous
//
#include <hip/hip_runtime.h>
#include <hip/hip_bf16.h>
#include <math.h>

#define B_SZ 2048
#define NF 1024
#define NH 2048
#define NCq 128
#define MMq 20
#define NY 2580            // M*NC+M
#define NYPAD 2688         // 21*128
#define NYP2 2592          // bf16 partial row stride (5184 B, 16B-aligned rows)
#define QP_ITERS 40        // HW-validated R17: absmax bit-identical at 40

#define XN4  (B_SZ * NF / 4)
#define W1N4 (NH * NF / 4)
#define W2N4 (NY * NH / 4)
#define CVT_TOT (XN4 + W1N4 + W2N4)

#define YBYTES ((size_t)B_SZ * NYP2 * 2)        // 10.6 MB per bf16 partial
#define WS_Y0  27787264
#define WS_NEED_SPLIT (WS_Y0 + 2 * YBYTES)

typedef unsigned short u16;
typedef __bf16 bf16x8 __attribute__((ext_vector_type(8)));
typedef float f32x4 __attribute__((ext_vector_type(4)));
typedef unsigned short u16x8 __attribute__((ext_vector_type(8)));

static __device__ __forceinline__ u16 f32_to_bf16(float f) {
  unsigned u = __float_as_uint(f);
  u += 0x7FFFu + ((u >> 16) & 1u);
  return (u16)(u >> 16);
}

static __device__ __forceinline__ float b2f(u16 u) {
  return __uint_as_float((unsigned)u << 16);
}

static __device__ __forceinline__ float bcast(float v, int lane) {
  return __uint_as_float(__builtin_amdgcn_readlane(__float_as_uint(v), lane));
}

static __device__ __forceinline__ void gload16(const void* g, void* lds) {
  __builtin_amdgcn_global_load_lds(
      (const __attribute__((address_space(1))) void*)g,
      (__attribute__((address_space(3))) void*)lds, 16, 0, 0);
}

// ---------------- single fused convert: x | W1 | W2(real rows) ----------------
__global__ __launch_bounds__(256) void cvt_all_kernel(const float* __restrict__ x,
                                                      const float* __restrict__ W1,
                                                      const float* __restrict__ W2,
                                                      u16* __restrict__ xb,
                                                      u16* __restrict__ w1b,
                                                      u16* __restrict__ w2b) {
  const int i = blockIdx.x * 256 + threadIdx.x;
  const float* src;
  u16* dst;
  int j;
  if (i < XN4)              { src = x;  dst = xb;  j = i; }
  else if (i < XN4 + W1N4)  { src = W1; dst = w1b; j = i - XN4; }
  else                      { src = W2; dst = w2b; j = i - XN4 - W1N4; }
  float4 v = ((const float4*)src)[j];
  ushort4 o;
  o.x = f32_to_bf16(v.x); o.y = f32_to_bf16(v.y);
  o.z = f32_to_bf16(v.z); o.w = f32_to_bf16(v.w);
  ((ushort4*)dst)[j] = o;
}

// ---------------- GEMM: C = A(M x lda) * B(N x lda)^T + bias, tile 64x128 ----
// R15-EXACT structure (empirical best of the R8-R17 schedule sweep): depth-2
// counted-vmcnt(6) pipeline, two barriers/iter, 48KB LDS; T2 both-sides
// 16B-chunk swizzle (0 bank conflicts verified); bijective XCD swizzle.
// Output is ALWAYS bf16 (OUTMODE 1 partials too -- cuts split-K WRITE 42->10.6MB).
// SPLIT-K (OUTMODE 1, nhalf>0): s=1 blocks -> second K-half into C1, no bias.
// OUTMODE 0: relu then store. OUTMODE 1: col<ncols guard, bias on s==0 only.
template<int KEXT, int OUTMODE>
__global__ __launch_bounds__(256) void gemm_bt_kernel(
    const u16* __restrict__ A, const u16* __restrict__ Bm,
    const float* __restrict__ bias,
    u16* __restrict__ C0, u16* __restrict__ C1,
    int ldc, int ncols, int nxt, int lda, int nhalf) {
  __shared__ u16 As[2][2][64 * 32];    // [buf][ksub] 4 KB planes, 16 KB
  __shared__ u16 Bs[2][2][128 * 32];   // [buf][ksub] 8 KB planes, 32 KB
  const int tid = threadIdx.x;
  const int w = tid >> 6;
  const int l = tid & 63;

  // bijective XCD swizzle: gridDim.x % 8 == 0
  const int chunk = gridDim.x >> 3;
  const int swz = (blockIdx.x & 7) * chunk + (blockIdx.x >> 3);
  int s = 0, idx = swz;
  if (OUTMODE == 1 && nhalf > 0) { s = swz >= nhalf; idx = swz - s * nhalf; }
  const int m0 = (idx / nxt) * 64;
  const int n0 = (idx % nxt) * 128;
  const u16* Ab = A  + (size_t)s * KEXT;
  const u16* Bb = Bm + (size_t)s * KEXT;
  u16* Cw = (OUTMODE == 0) ? C0 : (s ? C1 : C0);

  // staging: physical chunk p per plane -> row p>>2, phys-kp p&3;
  // logical k-chunk = (p&3) ^ ((row>>1)&3)
  const int srow = tid >> 2;
  const int kps = (tid & 3) ^ ((tid >> 3) & 3);
  const u16* gA0 = Ab + (size_t)(m0 + srow) * lda + kps * 8;
  const u16* gB0 = Bb + (size_t)(n0 + srow) * lda + kps * 8;
  const u16* gB1 = Bb + (size_t)(n0 + 64 + srow) * lda + kps * 8;
  char* lA = (char*)As;
  char* lB = (char*)Bs;
  const int lbW = w * 1024;            // wave-uniform byte offset within a plane

  // wave -> 32x64 output sub-tile: wm in {0,32}, wn in {0,64}
  const int wm = (w >> 1) * 32, wn = (w & 1) * 64;
  const int lrow = l & 15;
  const int kc = ((l >> 4) ^ ((lrow >> 1) & 3)) * 16;   // swizzled 16B chunk
  int aoff[2], boff[4];
#pragma unroll
  for (int i = 0; i < 2; ++i) aoff[i] = (wm + i * 16 + lrow) * 64 + kc;
#pragma unroll
  for (int i = 0; i < 4; ++i) boff[i] = (wn + i * 16 + lrow) * 64 + kc;

  f32x4 acc[2][4];
#pragma unroll
  for (int i = 0; i < 2; ++i)
#pragma unroll
    for (int j = 0; j < 4; ++j) acc[i][j] = (f32x4){0.f, 0.f, 0.f, 0.f};

  constexpr int NT = KEXT / 64;

  auto STAGE = [&](int t, int buf) {   // 6 gload16
#pragma unroll
    for (int ks = 0; ks < 2; ++ks) {
      const int koff = t * 64 + ks * 32;
      gload16(gA0 + koff, lA + buf * 8192  + ks * 4096 + lbW);
      gload16(gB0 + koff, lB + buf * 16384 + ks * 8192 + lbW);
      gload16(gB1 + koff, lB + buf * 16384 + ks * 8192 + 4096 + lbW);
    }
  };
  auto COMPUTE = [&](int buf) {        // 12 ds_read_b128 + 16 MFMA
#pragma unroll
    for (int ks = 0; ks < 2; ++ks) {
      const char* pa = lA + buf * 8192  + ks * 4096;
      const char* pb = lB + buf * 16384 + ks * 8192;
      bf16x8 af[2], bfr[4];
#pragma unroll
      for (int i = 0; i < 2; ++i) af[i] = *(const bf16x8*)(pa + aoff[i]);
#pragma unroll
      for (int i = 0; i < 4; ++i) bfr[i] = *(const bf16x8*)(pb + boff[i]);
#pragma unroll
      for (int mi = 0; mi < 2; ++mi)
#pragma unroll
        for (int ni = 0; ni < 4; ++ni)
          acc[mi][ni] = __builtin_amdgcn_mfma_f32_16x16x32_bf16(af[mi], bfr[ni], acc[mi][ni], 0, 0, 0);
    }
  };

  // prologue: 2 tiles in flight (12 loads)
  STAGE(0, 0);
  STAGE(1, 1);

  for (int kt = 0; kt < NT - 1; ++kt) {
    asm volatile("s_waitcnt vmcnt(6)" ::: "memory");   // tile kt retired; kt+1 in flight
    __builtin_amdgcn_s_barrier();                      // all waves' writes visible
    __builtin_amdgcn_sched_barrier(0);
    COMPUTE(kt & 1);
    __builtin_amdgcn_sched_barrier(0);
    __builtin_amdgcn_s_barrier();                      // all waves done reading buf
    __builtin_amdgcn_sched_barrier(0);
    if (kt + 2 < NT) STAGE(kt + 2, kt & 1);            // refill freed buffer
  }
  asm volatile("s_waitcnt vmcnt(0)" ::: "memory");     // peeled last iteration
  __builtin_amdgcn_s_barrier();
  __builtin_amdgcn_sched_barrier(0);
  COMPUTE((NT - 1) & 1);

  // epilogue: C row = m0+wm+mi*16+(l>>4)*4+r ; col = n0+wn+ni*16+(l&15)
#pragma unroll
  for (int mi = 0; mi < 2; ++mi) {
    const int row = m0 + wm + mi * 16 + (l >> 4) * 4;
#pragma unroll
    for (int ni = 0; ni < 4; ++ni) {
      const int col = n0 + wn + ni * 16 + (l & 15);
      if (OUTMODE == 1 && col >= ncols) continue;
      const float bv = (OUTMODE == 0 || s == 0) ? bias[col] : 0.f;
#pragma unroll
      for (int r = 0; r < 4; ++r) {
        float v = acc[mi][ni][r] + bv;
        if (OUTMODE == 0) v = fmaxf(v, 0.f);
        Cw[(size_t)(row + r) * ldc + col] = f32_to_bf16(v);
      }
    }
  }
}

// ---------------- QP solve + log_softmax ----------------
// 4 waves/block, ONE problem per wave. Partials are bf16 (stride NYP2);
// y = y0 (+ y1 if split-K), converted+summed in f32 during G-staging.
__global__ __launch_bounds__(256) void qp_kernel(const u16* __restrict__ y0,
                                                 const u16* __restrict__ y1,
                                                 float* __restrict__ out) {
  __shared__ float Gs[4][MMq][132];    // row pad 132: staging/epilogue conflict-free
  __shared__ float GGs[4][MMq][21];    // row pad 21: gcd(21,32)=1, conflict-free
  __shared__ float cs[4][MMq];
  const int tid = threadIdx.x;
  const int wid = tid >> 6, l = tid & 63;
  const int b = blockIdx.x * 4 + wid;
  const u16* yb0 = y0 + (size_t)b * NYP2;
  const u16* yb1 = y1 ? y1 + (size_t)b * NYP2 : nullptr;

  // stage G (20x128) -- own wave only; bf16->f32 convert + split-K sum
  for (int idx = l; idx < MMq * NCq / 8; idx += 64) {   // 320 u16x8 chunks
    const int r = idx >> 4;            // 16 chunks per 128-col row
    const int kk = (idx & 15) * 8;
    u16x8 v0 = *(const u16x8*)(yb0 + idx * 8);
    float f[8];
#pragma unroll
    for (int q = 0; q < 8; ++q) f[q] = b2f(v0[q]);
    if (yb1) {
      u16x8 v1 = *(const u16x8*)(yb1 + idx * 8);
#pragma unroll
      for (int q = 0; q < 8; ++q) f[q] += b2f(v1[q]);
    }
    *(float4*)&Gs[wid][r][kk]     = (float4){f[0], f[1], f[2], f[3]};
    *(float4*)&Gs[wid][r][kk + 4] = (float4){f[4], f[5], f[6], f[7]};
  }

  // GG = G G^T (upper triangle, mirrored) -- own wave
  for (int idx = l; idx < 210; idx += 64) {
    int i = 0, rem = idx;
    while (rem >= MMq - i) { rem -= MMq - i; ++i; }
    const int j = i + rem;
    float s = 0.f;
    for (int kk = 0; kk < NCq; kk += 4) {
      float4 a = *(const float4*)&Gs[wid][i][kk];
      float4 c4 = *(const float4*)&Gs[wid][j][kk];
      s += a.x * c4.x + a.y * c4.y + a.z * c4.z + a.w * c4.w;
    }
    GGs[wid][i][j] = s;
    GGs[wid][j][i] = s;
  }
  // c_i = sum_j G_ij + h_i
  if (l < MMq) {
    float s = 0.f;
    for (int kk = 0; kk < NCq; kk += 4) {
      float4 a = *(const float4*)&Gs[wid][l][kk];
      s += (a.x + a.y) + (a.z + a.w);
    }
    float h = b2f(yb0[MMq * NCq + l]);
    if (yb1) h += b2f(yb1[MMq * NCq + l]);
    cs[wid][l] = s + h;
  }

  const bool act = (l < MMq);
  float gg[MMq];
#pragma unroll
  for (int j = 0; j < MMq; ++j) gg[j] = act ? GGs[wid][l][j] : 0.f;
  const float ci = act ? cs[wid][l] : 0.f;

  // L = max_i sum_j |GG_ij| (inf-norm >= lambda_max; fixed point step-independent)
  float rs = 0.f;
#pragma unroll
  for (int j = 0; j < MMq; ++j) rs += fabsf(gg[j]);
#pragma unroll
  for (int m = 1; m < 64; m <<= 1) rs = fmaxf(rs, __shfl_xor(rs, m, 64));
  const float invL = 1.0f / (rs + 1e-6f);

  // FISTA, momentum beta_k = k/(k+3)
  float lam = 0.f, yv = 0.f, fi = 0.f;
  for (int it = 0; it < QP_ITERS; ++it) {
    float ys[MMq];
#pragma unroll
    for (int j = 0; j < MMq; ++j) ys[j] = bcast(yv, j);   // 20x v_readlane -> SGPR
    float g0 = ci, g1 = 0.f, g2 = 0.f, g3 = 0.f;
#pragma unroll
    for (int j = 0; j < MMq; j += 4) {
      g0 = fmaf(gg[j + 0], ys[j + 0], g0);
      g1 = fmaf(gg[j + 1], ys[j + 1], g1);
      g2 = fmaf(gg[j + 2], ys[j + 2], g2);
      g3 = fmaf(gg[j + 3], ys[j + 3], g3);
    }
    const float grad = (g0 + g1) + (g2 + g3);
    const float ln = fmaxf(fmaf(-grad, invL, yv), 0.f);
    const float beta = fi * __builtin_amdgcn_rcpf(fi + 3.0f);  // off critical path
    yv = fmaf(beta, ln - lam, ln);
    lam = ln;
    fi += 1.0f;
  }

  // broadcast lam to SGPRs; z_j = -(1 + sum_i G_ij lam_i); log_softmax over 128
  float ls[MMq];
#pragma unroll
  for (int j = 0; j < MMq; ++j) ls[j] = bcast(lam, j);

  float z0 = 1.f, z1 = 1.f;
#pragma unroll
  for (int ii = 0; ii < MMq; ++ii) {
    z0 = fmaf(Gs[wid][ii][l], ls[ii], z0);
    z1 = fmaf(Gs[wid][ii][l + 64], ls[ii], z1);
  }
  z0 = -z0; z1 = -z1;

  float mx = fmaxf(z0, z1);
#pragma unroll
  for (int m = 1; m < 64; m <<= 1) mx = fmaxf(mx, __shfl_xor(mx, m, 64));
  float sm = __expf(z0 - mx) + __expf(z1 - mx);
#pragma unroll
  for (int m = 1; m < 64; m <<= 1) sm += __shfl_xor(sm, m, 64);
  const float lse = mx + __logf(sm);
  float* ob = out + (size_t)b * NCq;
  ob[l] = z0 - lse;
  ob[l + 64] = z1 - lse;
}

// ---------------- launch ----------------
extern "C" void kernel_launch(void* const* d_in, const int* in_sizes, int n_in,
                              void* d_out, int out_size, void* d_ws, size_t ws_size,
                              hipStream_t stream) {
  const float* x  = (const float*)d_in[0];
  const float* W1 = (const float*)d_in[1];
  const float* b1 = (const float*)d_in[2];
  const float* W2 = (const float*)d_in[3];
  const float* b2 = (const float*)d_in[4];
  float* out = (float*)d_out;
  char* ws = (char*)d_ws;

  u16* xb  = (u16*)(ws);                         //  4 MiB
  u16* w1b = (u16*)(ws + 4194304);               //  4 MiB
  u16* w2b = (u16*)(ws + 8388608);               // 10.5 MiB (pad rows stale, never stored)
  u16* h1b = (u16*)(ws + 19398656);              //  8 MiB
  u16* yb0 = (u16*)(ws + WS_Y0);                 // 10.6 MiB bf16 partial 0 (with bias)
  u16* yb1 = (u16*)(ws + WS_Y0 + YBYTES);        // 10.6 MiB bf16 partial 1 (split only)

  const bool splitk = ws_size >= WS_NEED_SPLIT;

  cvt_all_kernel<<<CVT_TOT / 256, 256, 0, stream>>>(x, W1, W2, xb, w1b, w2b);

  // gemm1: K=1024 full, grid 512 (%8==0)
  gemm_bt_kernel<1024, 0><<<(NH / 128) * (B_SZ / 64), 256, 0, stream>>>(
      xb, w1b, b1, h1b, nullptr, NH, NH, NH / 128, NF, 0);

  if (splitk) {
    // gemm2 split-K=2: one launch, grid 1344 (%8==0); halves -> yb0 / yb1
    gemm_bt_kernel<1024, 1><<<2 * (NYPAD / 128) * (B_SZ / 64), 256, 0, stream>>>(
        h1b, w2b, b2, yb0, yb1, NYP2, NY, NYPAD / 128, NH,
        (NYPAD / 128) * (B_SZ / 64));
    qp_kernel<<<B_SZ / 4, 256, 0, stream>>>(yb0, yb1, out);
  } else {
    // fallback: single full-K gemm2 (bf16 out)
    gemm_bt_kernel<2048, 1><<<(NYPAD / 128) * (B_SZ / 64), 256, 0, stream>>>(
        h1b, w2b, b2, yb0, nullptr, NYP2, NY, NYPAD / 128, NH, 0);
    qp_kernel<<<B_SZ / 4, 256, 0, stream>>>(yb0, nullptr, out);
  }
}